// Round 1
// baseline (347.952 us; speedup 1.0000x reference)
//
#include <hip/hip_runtime.h>

// ClusteringLayer v2 on gfx950 — barrier-free wave-independent design.
// q = normalize(1/(1+dist2)), dist2 = xsq + csq - 2 x.c (exact fp32 xsq/csq;
// cross via bf16 MFMA, one-sided split x = x_hi + x_lo => 2 MFMA passes).
//
// Decomposition: each wave owns 16 rows x 256 cols. A-fragments built in
// registers straight from global (no LDS staging, no barriers, no bank
// conflicts). B (clusters) preconverted ONCE by a prep kernel into workspace
// in MFMA B-fragment order (bf16) + exact fp32 csq[256] table. Row sums are
// in-wave shfl_xor reductions. Only one trivial __syncthreads (csq table).

#define DIM 128
#define NK  256

typedef __attribute__((ext_vector_type(8))) short short8;
typedef __attribute__((ext_vector_type(4))) float floatx4;

__device__ __forceinline__ unsigned short bf16_rne(float f) {
    unsigned int u = __float_as_uint(f);
    return (unsigned short)((u + 0x7fffu + ((u >> 16) & 1u)) >> 16);
}
__device__ __forceinline__ float bf16_f(unsigned short h) {
    return __uint_as_float(((unsigned int)h) << 16);
}

// ---------------------------------------------------------------------------
// prep: blocks 0-7 pack C into B-fragment order: ushort16B frag index
//   gid = ct*256 + ks*64 + lane  holds  c_bf16[col = ct*16 + (lane&15)]
//                                        [k = ks*32 + (lane>>4)*8 + j], j=0..7
// block 8: exact fp32 csq[col] = sum_k c[col][k]^2.
// ---------------------------------------------------------------------------
__global__ void prep_clusters(const float* __restrict__ c,
                              unsigned short* __restrict__ wb,
                              float* __restrict__ wcsq)
{
    if (blockIdx.x < 8) {
        const int gid  = blockIdx.x * 512 + threadIdx.x;  // 0..4095
        const int lane = gid & 63;
        const int ks   = (gid >> 6) & 3;
        const int ct   = gid >> 8;
        const int lm   = lane & 15;
        const int q4   = lane >> 4;
        const int col  = ct * 16 + lm;
        const float4* cg = (const float4*)(c + col * DIM + ks * 32 + q4 * 8);
        float4 v0 = cg[0], v1 = cg[1];
        const float* f0 = (const float*)&v0;
        const float* f1 = (const float*)&v1;
        union { unsigned short u[8]; short8 v; } B;
        #pragma unroll
        for (int i = 0; i < 4; ++i) B.u[i] = bf16_rne(f0[i]);
        #pragma unroll
        for (int i = 0; i < 4; ++i) B.u[4 + i] = bf16_rne(f1[i]);
        ((short8*)wb)[gid] = B.v;
    } else {
        const int t = threadIdx.x;
        const int col = t >> 1, half = t & 1;
        const float4* cg = (const float4*)(c + col * DIM + half * 64);
        float s = 0.f;
        #pragma unroll
        for (int i = 0; i < 16; ++i) {
            float4 v = cg[i];
            s = fmaf(v.x, v.x, s); s = fmaf(v.y, v.y, s);
            s = fmaf(v.z, v.z, s); s = fmaf(v.w, v.w, s);
        }
        s += __shfl_xor(s, 1);   // partner thread, same col
        if (!half) wcsq[col] = s;
    }
}

// ---------------------------------------------------------------------------
// main: 256 threads = 4 independent waves; wave w -> rows [bid*64+16w, +16).
// ---------------------------------------------------------------------------
__global__ __launch_bounds__(256, 3) void cluster_q_v2(
    const float* __restrict__ x,
    const unsigned short* __restrict__ wb,
    const float* __restrict__ wcsq,
    float* __restrict__ out)
{
    __shared__ float csq_s[NK];
    const int tid  = threadIdx.x;
    csq_s[tid] = wcsq[tid];          // 256 threads load 256-entry table

    const int wave = tid >> 6;
    const int lane = tid & 63;
    const int lm   = lane & 15;      // A row / C col within tile
    const int q4   = lane >> 4;
    const size_t row0 = (size_t)blockIdx.x * 64 + wave * 16;

    // ---- A fragments (hi/lo) in registers + exact fp32 row norm ----
    // lane covers row lm, k = ks*32 + q4*8 + j
    short8 ah[4], al[4];
    float xq = 0.f;
    const float* xrow = x + (row0 + lm) * DIM;
    #pragma unroll
    for (int ks = 0; ks < 4; ++ks) {
        const float4* xg = (const float4*)(xrow + ks * 32 + q4 * 8);
        float4 v0 = xg[0], v1 = xg[1];
        const float* f0 = (const float*)&v0;
        const float* f1 = (const float*)&v1;
        union { unsigned short u[8]; short8 v; } H, L;
        #pragma unroll
        for (int i = 0; i < 4; ++i) {
            float f = f0[i];
            xq = fmaf(f, f, xq);
            unsigned short h = bf16_rne(f);
            H.u[i] = h;
            L.u[i] = bf16_rne(f - bf16_f(h));
        }
        #pragma unroll
        for (int i = 0; i < 4; ++i) {
            float f = f1[i];
            xq = fmaf(f, f, xq);
            unsigned short h = bf16_rne(f);
            H.u[4 + i] = h;
            L.u[4 + i] = bf16_rne(f - bf16_f(h));
        }
        ah[ks] = H.v;
        al[ks] = L.v;
    }
    // lane holds k-subset for fixed q4; sum over the 4 q4 groups -> full ||x_row||^2
    xq += __shfl_xor(xq, 16);
    xq += __shfl_xor(xq, 32);

    // ---- K loop: 16 col-tiles, B-frags streamed from L2-resident workspace ----
    floatx4 acc[16];
    #pragma unroll
    for (int ct = 0; ct < 16; ++ct) {
        const short8* bp = (const short8*)wb + (ct * 256 + lane);
        floatx4 a = (floatx4){0.f, 0.f, 0.f, 0.f};
        #pragma unroll
        for (int ks = 0; ks < 4; ++ks) {
            short8 b = bp[ks * 64];   // fully coalesced: 64 lanes x 16B contiguous
            a = __builtin_amdgcn_mfma_f32_16x16x32_bf16(ah[ks], b, a, 0, 0, 0);
            a = __builtin_amdgcn_mfma_f32_16x16x32_bf16(al[ks], b, a, 0, 0, 0);
        }
        acc[ct] = a;
    }

    __syncthreads();   // csq_s ready (placed late: zero wait in practice)

    // xsq for this lane's C rows (row = q4*4 + r lives in lanes with lm == that)
    float xs4[4];
    #pragma unroll
    for (int r = 0; r < 4; ++r) xs4[r] = __shfl(xq, q4 * 4 + r);

    // ---- epilogue: q = 1/(1+dist2), in-wave row sums ----
    float rsum[4] = {0.f, 0.f, 0.f, 0.f};
    #pragma unroll
    for (int ct = 0; ct < 16; ++ct) {
        const float cq = csq_s[ct * 16 + lm];
        #pragma unroll
        for (int r = 0; r < 4; ++r) {
            float d2 = fmaf(-2.f, acc[ct][r], xs4[r] + cq);
            d2 = fmaxf(d2, 0.f);
            float q = __builtin_amdgcn_rcpf(1.f + d2);
            acc[ct][r] = q;
            rsum[r] += q;
        }
    }
    #pragma unroll
    for (int r = 0; r < 4; ++r) {
        rsum[r] += __shfl_xor(rsum[r], 1);
        rsum[r] += __shfl_xor(rsum[r], 2);
        rsum[r] += __shfl_xor(rsum[r], 4);
        rsum[r] += __shfl_xor(rsum[r], 8);
        rsum[r] = __builtin_amdgcn_rcpf(rsum[r]);
    }

    // ---- normalize + store (4 base addrs, imm-offset folded stores) ----
    #pragma unroll
    for (int r = 0; r < 4; ++r) {
        float* op = out + (row0 + q4 * 4 + r) * NK + lm;
        const float inv = rsum[r];
        #pragma unroll
        for (int ct = 0; ct < 16; ++ct)
            op[ct * 16] = acc[ct][r] * inv;
    }
}

extern "C" void kernel_launch(void* const* d_in, const int* in_sizes, int n_in,
                              void* d_out, int out_size, void* d_ws, size_t ws_size,
                              hipStream_t stream) {
    const float* x = (const float*)d_in[0];   // [200000, 128] fp32
    const float* c = (const float*)d_in[1];   // [256, 128] fp32
    float* out = (float*)d_out;               // [200000, 256] fp32
    unsigned short* wb = (unsigned short*)d_ws;            // 64 KiB packed B
    float* wcsq = (float*)((char*)d_ws + 65536);           // 1 KiB csq
    const int N = in_sizes[0] / DIM;          // 200000 = 3125 * 64

    prep_clusters<<<dim3(9), dim3(512), 0, stream>>>(c, wb, wcsq);
    cluster_q_v2<<<dim3(N / 64), dim3(256), 0, stream>>>(x, wb, wcsq, out);
}